// Round 6
// baseline (87.685 us; speedup 1.0000x reference)
//
#include <hip/hip_runtime.h>
#include <math.h>

// fBM via truncated generalized Schur (Toeplitz Cholesky) + convolution tail.
//
// R4 post-mortem: kernel ~32us (out of profile top-5; timed region dominated by
// harness ws-poison fills ~55us fixed). Remaining: serial Schur 128x~130cyc
// (bpermute latency-bound), f64 pow init ~3us.
// R5 (recompile of R4 theory; CUDA-ism intrinsics -> std names):
// (1) 2-step fused Schur — both reflection coefficients from readlanes
//     upfront (r1 = g2[1]/g1[0]; r2 = (g1[0]g2[2]-g2[1]g1[1])/(g1[0]^2-g2[1]^2)),
//     6 bpermutes issued concurrently -> ONE ~120cyc LDS wait per 2 columns.
//     g1'' = g1 - r1 s1g2 - r2 s2g2 + r1r2 s1g1; g2'' = s2g2 - r1 s1g1 - r2 g1
//     + r1r2 s1g2; column k+1 = g1 - r1 s1g2 (free).
// (2) f32 series covariance init (no f64 pow): k>=8:
//     R = 0.5 a(a-1) k^{a-2} (1 + c2/k^2 + c3/k^4), c2=(a-2)(a-3)/12,
//     c3=(a-2)(a-3)(a-4)(a-5)/360 — avoids f32 second-difference cancellation;
//     k<8 direct f32 powf (no cancellation at small k).

#define TM1 1023
#define NTH 256
#define K0  128

__device__ __forceinline__ float bperm(int a, float v) {
    return __int_as_float(__builtin_amdgcn_ds_bpermute(a, __float_as_int(v)));
}
__device__ __forceinline__ float rdlane(float v, int s) {
    return __int_as_float(__builtin_amdgcn_readlane(__float_as_int(v), s));
}
// mod-4 deinterleaved slot for us storage: plane (k&3), index (k>>2)
__device__ __forceinline__ int uslot(int k) { return ((k & 3) << 8) | (k >> 2); }

__global__ __launch_bounds__(NTH, 1)
void fbm_schur_kernel(const float* __restrict__ alpha,
                      const float* __restrict__ tau,
                      const float* __restrict__ diffusion,
                      const float* __restrict__ du,
                      float* __restrict__ out)
{
    const int b   = blockIdx.x;
    const int tid = threadIdx.x;
    const int w   = tid >> 6;
    const int l   = tid & 63;

    __shared__ float  colD[K0 * 128];                 // raw head columns, 64 KB
    __shared__ float4 us4[1024];                      // du*sd, plane-permuted, 16 KB
    __shared__ float  yx[1024], yy[1024], yz[1024];   // dx accumulators, 12 KB
    __shared__ float  Lc[128];                        // converged normalized column
    __shared__ float  wtot[12];

    const float sd = sqrtf(diffusion[b]);
    const float* dub = du + (size_t)b * (TM1 * 3);

    // ---- stage du*sd into plane-permuted us4; zero y ----
    for (int e = tid; e < TM1 * 3; e += NTH) {
        int k = e / 3, d = e - 3 * k;
        ((float*)&us4[uslot(k)])[d] = dub[e] * sd;
    }
    for (int i = tid; i < 1024; i += NTH) { yx[i] = 0.f; yy[i] = 0.f; yz[i] = 0.f; }

    // ---- generator init (wave 0; f32 series covariance) ----
    float g1a = 0.f, g1b = 0.f, g2a = 0.f, g2b = 0.f;
    if (w == 0) {
        const float af = alpha[b];
        const float tf = tau[b];
        const float c2 = (af - 2.f) * (af - 3.f) * (1.f / 12.f);
        const float c3 = (af - 2.f) * (af - 3.f) * (af - 4.f) * (af - 5.f) * (1.f / 360.f);
        const float lead = 0.5f * af * (af - 1.f);
        auto covf = [&](int k) -> float {
            if (k == 0) return 1.0f;
            float kf = (float)k;
            float R;
            if (k < 8) {
                float pm = (k == 1) ? 0.f : powf(kf - 1.f, af);
                R = 0.5f * (powf(kf + 1.f, af) + pm - 2.f * powf(kf, af));
            } else {
                float x2 = 1.f / (kf * kf);
                float poly = 1.f + x2 * (c2 + x2 * c3);
                float kp = exp2f((af - 2.f) * log2f(kf));
                R = lead * kp * poly;
            }
            if (kf >= tf) R *= exp2f((tf - kf) * 1.44269504f);
            return R;
        };
        g1a = covf(l);
        g1b = covf(l + 64);
        g2a = (l == 0) ? 0.f : g1a;
        g2b = g1b;
    }
    __syncthreads();

    // ---- serial Schur: K0 columns, 2 per iteration (wave 0 only) ----
    if (w == 0) {
        const int ad1 = ((l + 1) & 63) << 2;
        const int ad2 = ((l + 2) & 63) << 2;
        for (int k = 0; k < K0; k += 2) {
            // shifted vectors (issue all 6 bpermutes back-to-back, wait once)
            float g1a1 = bperm(ad1, g1a);
            float g1b1 = bperm(ad1, g1b);
            float g2a1 = bperm(ad1, g2a);
            float g2b1 = bperm(ad1, g2b);
            float g2a2 = bperm(ad2, g2a);
            float g2b2 = bperm(ad2, g2b);

            // both reflection coefficients from readlanes (overlaps LDS wait)
            float s10 = rdlane(g1a, 0);
            float s11 = rdlane(g1a, 1);
            float s21 = rdlane(g2a, 1);
            float s22 = rdlane(g2a, 2);
            float r1  = s21 * __builtin_amdgcn_rcpf(s10);
            float r2  = fmaf(s10, s22, -s21 * s11) *
                        __builtin_amdgcn_rcpf(fmaf(s10, s10, -s21 * s21));
            float r12 = r1 * r2;

            // wrap values for window-boundary lanes
            float wg1b0 = rdlane(g1b, 0);
            float wg2b0 = rdlane(g2b, 0);
            float wg2b1 = rdlane(g2b, 1);
            if (l == 62) { g2a2 = wg2b0; g2b2 = 0.f; }
            if (l == 63) {
                g1a1 = wg1b0; g1b1 = 0.f;
                g2a1 = wg2b0; g2b1 = 0.f;
                g2a2 = wg2b1; g2b2 = 0.f;
            }

            // column k (raw) and column k+1 = g1 - r1*s1g2
            float c1a = fmaf(-r1, g2a1, g1a);
            float c1b = fmaf(-r1, g2b1, g1b);
            colD[k * 128 + l]            = g1a;
            colD[k * 128 + 64 + l]       = g1b;
            colD[(k + 1) * 128 + l]      = c1a;
            colD[(k + 1) * 128 + 64 + l] = c1b;

            // fused 2-step state update
            float n1a = fmaf(r12, g1a1, fmaf(-r2, g2a2, c1a));
            float n1b = fmaf(r12, g1b1, fmaf(-r2, g2b2, c1b));
            float n2a = fmaf(r12, g2a1, fmaf(-r1, g1a1, fmaf(-r2, g1a, g2a2)));
            float n2b = fmaf(r12, g2b1, fmaf(-r1, g1b1, fmaf(-r2, g1b, g2b2)));
            g1a = n1a; g1b = n1b;
            g2a = n2a; g2b = n2b;
        }
        // converged column, normalized
        float sc = __frsqrt_rn(rdlane(g1a, 0));
        Lc[l]      = g1a * sc;
        Lc[64 + l] = g1b * sc;
    }
    __syncthreads();

    // ---- head matvec: columns 0..127, rows 0..255 (thread = row) ----
    {
        float4 v0 = us4[uslot(l)];
        float4 v1 = us4[uslot(64 + l)];
        float i0 = __frsqrt_rn(colD[l * 128]);
        float i1 = __frsqrt_rn(colD[(64 + l) * 128]);
        float ucx0 = v0.x * i0, ucy0 = v0.y * i0, ucz0 = v0.z * i0;
        float ucx1 = v1.x * i1, ucy1 = v1.y * i1, ucz1 = v1.z * i1;

        float ax = 0.f, ay = 0.f, az = 0.f;
        #pragma unroll 4
        for (int k2 = 0; k2 < 64; ++k2) {
            int p = tid - k2;
            float v = colD[k2 * 128 + p];
            v = ((unsigned)p < 128u) ? v : 0.f;
            ax = fmaf(v, rdlane(ucx0, k2), ax);
            ay = fmaf(v, rdlane(ucy0, k2), ay);
            az = fmaf(v, rdlane(ucz0, k2), az);
        }
        #pragma unroll 4
        for (int k2 = 64; k2 < 128; ++k2) {
            int p = tid - k2;
            float v = colD[k2 * 128 + p];
            v = ((unsigned)p < 128u) ? v : 0.f;
            ax = fmaf(v, rdlane(ucx1, k2 - 64), ax);
            ay = fmaf(v, rdlane(ucy1, k2 - 64), ay);
            az = fmaf(v, rdlane(ucz1, k2 - 64), az);
        }
        yx[tid] = ax; yy[tid] = ay; yz[tid] = az;
    }
    __syncthreads();

    // ---- tail: columns 128..1022 all equal Lc => convolution ----
    {
        float lca = Lc[l], lcb = Lc[64 + l];
        const int B = K0 + 4 * tid;                  // 4 consecutive rows
        float4 q0 = us4[uslot(B + 0)];
        float4 q1 = us4[uslot(B + 1)];
        float4 q2 = us4[uslot(B + 2)];
        float4 q3 = us4[uslot(B + 3)];
        float a0x=0,a0y=0,a0z=0, a1x=0,a1y=0,a1z=0;
        float a2x=0,a2y=0,a2z=0, a3x=0,a3y=0,a3z=0;

        #pragma unroll 8
        for (int j = 0; j < 64; ++j) {
            float lc = rdlane(lca, j);
            a0x = fmaf(lc, q0.x, a0x); a0y = fmaf(lc, q0.y, a0y); a0z = fmaf(lc, q0.z, a0z);
            a1x = fmaf(lc, q1.x, a1x); a1y = fmaf(lc, q1.y, a1y); a1z = fmaf(lc, q1.z, a1z);
            a2x = fmaf(lc, q2.x, a2x); a2y = fmaf(lc, q2.y, a2y); a2z = fmaf(lc, q2.z, a2z);
            a3x = fmaf(lc, q3.x, a3x); a3y = fmaf(lc, q3.y, a3y); a3z = fmaf(lc, q3.z, a3z);
            int xi = B - j - 1;
            float4 nv = us4[uslot(xi)];
            bool ok = (xi >= K0);
            nv.x = ok ? nv.x : 0.f; nv.y = ok ? nv.y : 0.f; nv.z = ok ? nv.z : 0.f;
            q3 = q2; q2 = q1; q1 = q0; q0 = nv;
        }
        #pragma unroll 8
        for (int j = 64; j < 128; ++j) {
            float lc = rdlane(lcb, j - 64);
            a0x = fmaf(lc, q0.x, a0x); a0y = fmaf(lc, q0.y, a0y); a0z = fmaf(lc, q0.z, a0z);
            a1x = fmaf(lc, q1.x, a1x); a1y = fmaf(lc, q1.y, a1y); a1z = fmaf(lc, q1.z, a1z);
            a2x = fmaf(lc, q2.x, a2x); a2y = fmaf(lc, q2.y, a2y); a2z = fmaf(lc, q2.z, a2z);
            a3x = fmaf(lc, q3.x, a3x); a3y = fmaf(lc, q3.y, a3y); a3z = fmaf(lc, q3.z, a3z);
            int xi = B - j - 1;
            float4 nv = us4[uslot(xi)];
            bool ok = (xi >= K0);
            nv.x = ok ? nv.x : 0.f; nv.y = ok ? nv.y : 0.f; nv.z = ok ? nv.z : 0.f;
            q3 = q2; q2 = q1; q1 = q0; q0 = nv;
        }
        if (B + 0 <= 1022) { yx[B+0] += a0x; yy[B+0] += a0y; yz[B+0] += a0z; }
        if (B + 1 <= 1022) { yx[B+1] += a1x; yy[B+1] += a1y; yz[B+1] += a1z; }
        if (B + 2 <= 1022) { yx[B+2] += a2x; yy[B+2] += a2y; yz[B+2] += a2z; }
        if (B + 3 <= 1022) { yx[B+3] += a3x; yy[B+3] += a3y; yz[B+3] += a3z; }
    }
    __syncthreads();

    // ---- cumsum (4-wave scan) + write [zeros; x] ----
    float cx = 0.f, cy = 0.f, cz = 0.f;
    for (int s = 0; s < 4; ++s) {
        int i = (w << 8) + (s << 6) + l;
        float sx = (i < TM1) ? yx[i] : 0.f;
        float sy = (i < TM1) ? yy[i] : 0.f;
        float sz = (i < TM1) ? yz[i] : 0.f;
        #pragma unroll
        for (int off = 1; off < 64; off <<= 1) {
            float tx = __shfl_up(sx, off);
            float ty = __shfl_up(sy, off);
            float tz = __shfl_up(sz, off);
            if (l >= off) { sx += tx; sy += ty; sz += tz; }
        }
        sx += cx; sy += cy; sz += cz;
        if (i < TM1) { yx[i] = sx; yy[i] = sy; yz[i] = sz; }
        cx = __shfl(sx, 63); cy = __shfl(sy, 63); cz = __shfl(sz, 63);
    }
    if (l == 0) { wtot[w * 3 + 0] = cx; wtot[w * 3 + 1] = cy; wtot[w * 3 + 2] = cz; }
    __syncthreads();

    float ox = 0.f, oy = 0.f, oz = 0.f;
    for (int q = 0; q < w; ++q) {
        ox += wtot[q * 3 + 0]; oy += wtot[q * 3 + 1]; oz += wtot[q * 3 + 2];
    }
    float* outb = out + (size_t)b * (TM1 + 1) * 3;
    for (int s = 0; s < 4; ++s) {
        int i = (w << 8) + (s << 6) + l;
        if (i < TM1) {
            outb[(i + 1) * 3 + 0] = yx[i] + ox;
            outb[(i + 1) * 3 + 1] = yy[i] + oy;
            outb[(i + 1) * 3 + 2] = yz[i] + oz;
        }
    }
    if (tid == 0) { outb[0] = 0.f; outb[1] = 0.f; outb[2] = 0.f; }
}

extern "C" void kernel_launch(void* const* d_in, const int* in_sizes, int n_in,
                              void* d_out, int out_size, void* d_ws, size_t ws_size,
                              hipStream_t stream)
{
    const float* alpha     = (const float*)d_in[0];
    const float* tau       = (const float*)d_in[1];
    const float* diffusion = (const float*)d_in[2];
    const float* du        = (const float*)d_in[3];
    float* out = (float*)d_out;
    const int BS = in_sizes[0];

    fbm_schur_kernel<<<dim3(BS), dim3(NTH), 0, stream>>>(
        alpha, tau, diffusion, du, out);
}